// Round 3
// baseline (317.975 us; speedup 1.0000x reference)
//
#include <hip/hip_runtime.h>
#include <math.h>

#define D 4096
#define NW 4                 // independent rows (waves) per block
#define NT (64 * NW)
#define EPS 1e-5f
#define EPS_SQRT 3.16227766016837933e-3f
#define LN2 0.69314718055994531f

// One wave per row, no barriers, no LDS, no per-lane row cache.
// x is read 3x: passes 2/3 re-read from L2/L3 (row is hot; input fits in 256MB L3).
// __launch_bounds__(NT, 8): cap VGPR at 64 -> 8 waves/SIMD ceiling.
__global__ __launch_bounds__(NT, 8) void lnn_kernel(const float* __restrict__ x,
                                                    const float* __restrict__ w,
                                                    const float* __restrict__ b,
                                                    float* __restrict__ out,
                                                    int rows) {
    const int lane = threadIdx.x & 63;
    const int wv   = threadIdx.x >> 6;
    const int row  = blockIdx.x * NW + wv;
    if (row >= rows) return;

    const float4* x4 = (const float4*)(x + (size_t)row * D);
    const float inv_d = 1.f / (float)D;

    // ---- pass 1: mean / var (streaming, nothing cached) ----
    float s = 0.f, s2 = 0.f;
#pragma unroll
    for (int c = 0; c < 16; ++c) {
        float4 f = x4[c * 64 + lane];
        float e0[4] = {f.x, f.y, f.z, f.w};
#pragma unroll
        for (int j = 0; j < 4; ++j) { s += e0[j]; s2 = fmaf(e0[j], e0[j], s2); }
    }
#pragma unroll
    for (int m = 32; m > 0; m >>= 1) {
        s  += __shfl_xor(s,  m, 64);
        s2 += __shfl_xor(s2, m, 64);
    }
    const float mean = s * inv_d;
    const float var  = s2 * inv_d - mean * mean;
    const float rstd = rsqrtf(var + EPS);
    const float nm   = -mean * rstd;

    // ---- pass 2: re-read x (L2-hot), 5 row-sums, nothing stored ----
    float s1 = 0.f, sxd = 0.f, sd = 0.f, sd2 = 0.f, sxd2 = 0.f;
#pragma unroll
    for (int c = 0; c < 16; ++c) {
        float4 f = x4[c * 64 + lane];
        float e0[4] = {f.x, f.y, f.z, f.w};
#pragma unroll
        for (int j = 0; j < 4; ++j) {
            float xs   = fmaf(e0[j], rstd, nm);
            float ab   = fabsf(xs);
            float onea = 1.f + ab;
            float L2   = __builtin_amdgcn_logf(onea);   // log2(1+|xs|)
            s1 += copysignf(L2, xs);                     // sum sign*L2 (xLN2 later)
            float l  = L2 * LN2;                         // natural log1p
            float dd = fmaf(onea, l, -ab);               // d = (1+|xs|)l1p - |xs|
            sxd = fmaf(xs, dd, sxd);
            sd += dd;
            sd2 = fmaf(dd, dd, sd2);
            float p1 = fmaf(onea, l * l, -(dd + dd));    // (1+|xs|)l1p^2 - 2d
            sxd2 = fmaf(ab, p1, sxd2);                   // xs*d2 = |xs|*p1
        }
    }
#pragma unroll
    for (int m = 32; m > 0; m >>= 1) {
        s1   += __shfl_xor(s1,   m, 64);
        sxd  += __shfl_xor(sxd,  m, 64);
        sd   += __shfl_xor(sd,   m, 64);
        sd2  += __shfl_xor(sd2,  m, 64);
        sxd2 += __shfl_xor(sxd2, m, 64);
    }

    // ---- row scalars (every lane, redundant, cheap) ----
    const float s1m   = s1 * (inv_d * LN2);
    const float dvar  = 2.f * sxd * inv_d;
    const float g1    = 0.5f * dvar - s1m;
    const float dmean = sd * inv_d;
    const float vard  = sd2 * inv_d - dmean * dmean;
    const float d2var = 2.f * (sxd2 * inv_d + vard);
    const float g2    = -0.5f * dvar * dvar + 0.5f * d2var;
    const float lm    = 1.f - g1 * __builtin_amdgcn_rcpf(g2 + EPS_SQRT);

    const float eta_p = lm;
    const float eta_n = 2.f - lm;
    const float ep = eta_p + ((eta_p >= 0.f) ? EPS_SQRT : -EPS_SQRT);
    const float en = eta_n + ((eta_n >= 0.f) ? EPS_SQRT : -EPS_SQRT);
    const bool  mp = fabsf(eta_p) <= EPS_SQRT;
    const bool  mn = fabsf(eta_n) <= EPS_SQRT;
    const float rp =  __builtin_amdgcn_rcpf(ep);
    const float rn = -__builtin_amdgcn_rcpf(en);

    float* orow = out + (size_t)row * D;
    const float4* w4 = (const float4*)w;
    const float4* b4 = (const float4*)b;

    // ---- pass 3: re-read x (L2-hot), recompute L2, transform + affine, store ----
    if (!(mp || mn)) {
        // fast path (overwhelmingly common): no tr2/mask selects
#pragma unroll
        for (int c = 0; c < 16; ++c) {
            float4 f  = x4[c * 64 + lane];
            float4 wf = w4[c * 64 + lane];
            float4 bf = b4[c * 64 + lane];
            float e0[4] = {f.x, f.y, f.z, f.w};
            float wa[4] = {wf.x, wf.y, wf.z, wf.w};
            float ba[4] = {bf.x, bf.y, bf.z, bf.w};
            float oa[4];
#pragma unroll
            for (int j = 0; j < 4; ++j) {
                float xs = fmaf(e0[j], rstd, nm);
                float L2 = __builtin_amdgcn_logf(1.f + fabsf(xs));
                bool pos = (xs >= 0.f);
                float e  = pos ? ep : en;
                float re = pos ? rp : rn;
                // tr1 = re*(exp2(e*L2)-1) = fma(re, exp2, -re)
                float tr = fmaf(re, __builtin_amdgcn_exp2f(e * L2), -re);
                oa[j] = fmaf(tr, wa[j], ba[j]);
            }
            float4 o = {oa[0], oa[1], oa[2], oa[3]};
            ((float4*)orow)[c * 64 + lane] = o;
        }
    } else {
        // general path with small-|eta| fallback
#pragma unroll
        for (int c = 0; c < 16; ++c) {
            float4 f  = x4[c * 64 + lane];
            float4 wf = w4[c * 64 + lane];
            float4 bf = b4[c * 64 + lane];
            float e0[4] = {f.x, f.y, f.z, f.w};
            float wa[4] = {wf.x, wf.y, wf.z, wf.w};
            float ba[4] = {bf.x, bf.y, bf.z, bf.w};
            float oa[4];
#pragma unroll
            for (int j = 0; j < 4; ++j) {
                float xs = fmaf(e0[j], rstd, nm);
                float L2 = __builtin_amdgcn_logf(1.f + fabsf(xs));
                bool pos = (xs >= 0.f);
                float e  = pos ? ep : en;
                float re = pos ? rp : rn;
                bool  m  = pos ? mp : mn;
                float tr1 = fmaf(re, __builtin_amdgcn_exp2f(e * L2), -re);
                float tr2 = copysignf(L2 * LN2, xs);   // sign * l1p
                float tr  = m ? tr2 : tr1;
                oa[j] = fmaf(tr, wa[j], ba[j]);
            }
            float4 o = {oa[0], oa[1], oa[2], oa[3]};
            ((float4*)orow)[c * 64 + lane] = o;
        }
    }
}

extern "C" void kernel_launch(void* const* d_in, const int* in_sizes, int n_in,
                              void* d_out, int out_size, void* d_ws, size_t ws_size,
                              hipStream_t stream) {
    const float* x = (const float*)d_in[0];
    const float* w = (const float*)d_in[1];
    const float* b = (const float*)d_in[2];
    float* out = (float*)d_out;
    const int rows = in_sizes[0] / D;            // 8192
    const int nblocks = (rows + NW - 1) / NW;    // 2048
    lnn_kernel<<<dim3(nblocks), dim3(NT), 0, stream>>>(x, w, b, out, rows);
}

// Round 4
// 275.985 us; speedup vs baseline: 1.1521x; 1.1521x over previous
//
#include <hip/hip_runtime.h>
#include <math.h>

#define D 4096
#define NW 4                 // independent rows (waves) per block
#define NT (64 * NW)
#define EPS 1e-5f
#define EPS_SQRT 3.16227766016837933e-3f
#define LN2 0.69314718055994531f

// One wave per row: no barriers, no LDS, butterfly reductions, x read ONCE.
// amdgpu_waves_per_eu(4,4): pin allocator target at 4 waves/SIMD (VGPR cap 128)
// so v[64] stays in registers. R2's spill came from launch_bounds(256,4) setting
// only a MIN -> backend chased 8 waves/EU (64-reg cap) and spilled the array.
__global__ __launch_bounds__(NT)
__attribute__((amdgpu_waves_per_eu(4, 4)))
void lnn_kernel(const float* __restrict__ x,
                const float* __restrict__ w,
                const float* __restrict__ b,
                float* __restrict__ out,
                int rows) {
    const int lane = threadIdx.x & 63;
    const int wv   = threadIdx.x >> 6;
    const int row  = blockIdx.x * NW + wv;
    if (row >= rows) return;

    const float4* x4 = (const float4*)(x + (size_t)row * D);
    const float inv_d = 1.f / (float)D;

    // ---- load 64 floats/lane as 16 float4; fold pass-1 sums into the load loop ----
    float v[64];
    float s = 0.f, s2 = 0.f;
#pragma unroll
    for (int c = 0; c < 16; ++c) {
        float4 f = x4[c * 64 + lane];
        v[c*4+0] = f.x; v[c*4+1] = f.y; v[c*4+2] = f.z; v[c*4+3] = f.w;
        s += f.x; s2 = fmaf(f.x, f.x, s2);
        s += f.y; s2 = fmaf(f.y, f.y, s2);
        s += f.z; s2 = fmaf(f.z, f.z, s2);
        s += f.w; s2 = fmaf(f.w, f.w, s2);
    }
#pragma unroll
    for (int m = 32; m > 0; m >>= 1) {
        s  += __shfl_xor(s,  m, 64);
        s2 += __shfl_xor(s2, m, 64);
    }
    const float mean = s * inv_d;
    const float var  = s2 * inv_d - mean * mean;
    const float rstd = rsqrtf(var + EPS);
    const float nm   = -mean * rstd;

    // ---- pass 2: xs, L2=log2(1+|xs|), 5 row-sums; overwrite v with copysign(L2,xs) ----
    float s1 = 0.f, sxd = 0.f, sd = 0.f, sd2 = 0.f, sxd2 = 0.f;
#pragma unroll
    for (int i = 0; i < 64; ++i) {
        float xs   = fmaf(v[i], rstd, nm);
        float ab   = fabsf(xs);
        float onea = 1.f + ab;
        float L2   = __builtin_amdgcn_logf(onea);   // v_log_f32: log2(1+|xs|)
        float sv   = copysignf(L2, xs);
        v[i] = sv;                                   // pass-3 needs only sign+L2
        s1 += sv;                                    // sum sign*L2 (xLN2 later)
        float l  = L2 * LN2;                         // natural log1p
        float dd = fmaf(onea, l, -ab);               // d = (1+|xs|)l1p - |xs|
        sxd = fmaf(xs, dd, sxd);
        sd += dd;
        sd2 = fmaf(dd, dd, sd2);
        float p1 = fmaf(onea, l * l, -(dd + dd));    // (1+|xs|)l1p^2 - 2d
        sxd2 = fmaf(ab, p1, sxd2);                   // xs*d2 = |xs|*p1
    }
#pragma unroll
    for (int m = 32; m > 0; m >>= 1) {
        s1   += __shfl_xor(s1,   m, 64);
        sxd  += __shfl_xor(sxd,  m, 64);
        sd   += __shfl_xor(sd,   m, 64);
        sd2  += __shfl_xor(sd2,  m, 64);
        sxd2 += __shfl_xor(sxd2, m, 64);
    }

    // ---- row scalars (every lane, redundant, cheap) ----
    const float s1m   = s1 * (inv_d * LN2);
    const float dvar  = 2.f * sxd * inv_d;
    const float g1    = 0.5f * dvar - s1m;
    const float dmean = sd * inv_d;
    const float vard  = sd2 * inv_d - dmean * dmean;
    const float d2var = 2.f * (sxd2 * inv_d + vard);
    const float g2    = -0.5f * dvar * dvar + 0.5f * d2var;
    const float lm    = 1.f - g1 * __builtin_amdgcn_rcpf(g2 + EPS_SQRT);

    const float eta_p = lm;
    const float eta_n = 2.f - lm;
    const float ep = eta_p + ((eta_p >= 0.f) ? EPS_SQRT : -EPS_SQRT);
    const float en = eta_n + ((eta_n >= 0.f) ? EPS_SQRT : -EPS_SQRT);
    const bool  mp = fabsf(eta_p) <= EPS_SQRT;
    const bool  mn = fabsf(eta_n) <= EPS_SQRT;
    const float rp =  __builtin_amdgcn_rcpf(ep);
    const float rn = -__builtin_amdgcn_rcpf(en);

    float* orow = out + (size_t)row * D;
    const float4* w4 = (const float4*)w;
    const float4* b4 = (const float4*)b;

    if (!(mp || mn)) {
        // fast path (overwhelmingly common): no tr2/mask selects
#pragma unroll
        for (int c = 0; c < 16; ++c) {
            float4 wf = w4[c * 64 + lane];
            float4 bf = b4[c * 64 + lane];
            float wa[4] = {wf.x, wf.y, wf.z, wf.w};
            float ba[4] = {bf.x, bf.y, bf.z, bf.w};
            float oa[4];
#pragma unroll
            for (int j = 0; j < 4; ++j) {
                float sv = v[c*4 + j];
                bool pos = (sv >= 0.f);
                float L2 = fabsf(sv);
                float e  = pos ? ep : en;
                float re = pos ? rp : rn;
                // tr1 = re*(exp2(e*L2)-1) = fma(re, exp2, -re)
                float tr = fmaf(re, __builtin_amdgcn_exp2f(e * L2), -re);
                oa[j] = fmaf(tr, wa[j], ba[j]);
            }
            float4 o = {oa[0], oa[1], oa[2], oa[3]};
            ((float4*)orow)[c * 64 + lane] = o;
        }
    } else {
        // general path with small-|eta| fallback
#pragma unroll
        for (int c = 0; c < 16; ++c) {
            float4 wf = w4[c * 64 + lane];
            float4 bf = b4[c * 64 + lane];
            float wa[4] = {wf.x, wf.y, wf.z, wf.w};
            float ba[4] = {bf.x, bf.y, bf.z, bf.w};
            float oa[4];
#pragma unroll
            for (int j = 0; j < 4; ++j) {
                float sv = v[c*4 + j];
                bool pos = (sv >= 0.f);
                float L2 = fabsf(sv);
                float e  = pos ? ep : en;
                float re = pos ? rp : rn;
                bool  m  = pos ? mp : mn;
                float tr1 = fmaf(re, __builtin_amdgcn_exp2f(e * L2), -re);
                float tr2 = sv * LN2;                // sign * l1p
                float tr  = m ? tr2 : tr1;
                oa[j] = fmaf(tr, wa[j], ba[j]);
            }
            float4 o = {oa[0], oa[1], oa[2], oa[3]};
            ((float4*)orow)[c * 64 + lane] = o;
        }
    }
}

extern "C" void kernel_launch(void* const* d_in, const int* in_sizes, int n_in,
                              void* d_out, int out_size, void* d_ws, size_t ws_size,
                              hipStream_t stream) {
    const float* x = (const float*)d_in[0];
    const float* w = (const float*)d_in[1];
    const float* b = (const float*)d_in[2];
    float* out = (float*)d_out;
    const int rows = in_sizes[0] / D;            // 8192
    const int nblocks = (rows + NW - 1) / NW;    // 2048
    lnn_kernel<<<dim3(nblocks), dim3(NT), 0, stream>>>(x, w, b, out, rows);
}

// Round 5
// 233.247 us; speedup vs baseline: 1.3633x; 1.1832x over previous
//
#include <hip/hip_runtime.h>
#include <math.h>

#define D 4096
#define NT 64                // one wave per block, one row per wave
#define EPS 1e-5f
#define EPS_SQRT 3.16227766016837933e-3f
#define LN2 0.69314718055994531f

// One wave per row. Row cached in LDS (16 KB) -- the compiler cannot spill LDS.
// No barriers anywhere: single-wave workgroup, LDS ordering via lgkmcnt,
// reductions via __shfl_xor butterflies.
__global__ __launch_bounds__(NT) void lnn_kernel(const float* __restrict__ x,
                                                 const float* __restrict__ w,
                                                 const float* __restrict__ b,
                                                 float* __restrict__ out,
                                                 int rows) {
    const int lane = threadIdx.x;        // 0..63
    const int row  = blockIdx.x;
    if (row >= rows) return;

    __shared__ float buf[D];             // raw x, then overwritten with copysign(L2,xs)
    float4* s4 = (float4*)buf;

    const float4* x4 = (const float4*)(x + (size_t)row * D);
    const float inv_d = 1.f / (float)D;

    // ---- pass 1: stream x global->LDS, accumulate mean/var in flight ----
    float s = 0.f, s2 = 0.f;
#pragma unroll
    for (int c = 0; c < 16; ++c) {
        float4 f = x4[c * 64 + lane];
        s4[c * 64 + lane] = f;
        s += f.x; s2 = fmaf(f.x, f.x, s2);
        s += f.y; s2 = fmaf(f.y, f.y, s2);
        s += f.z; s2 = fmaf(f.z, f.z, s2);
        s += f.w; s2 = fmaf(f.w, f.w, s2);
    }
#pragma unroll
    for (int m = 32; m > 0; m >>= 1) {
        s  += __shfl_xor(s,  m, 64);
        s2 += __shfl_xor(s2, m, 64);
    }
    const float mean = s * inv_d;
    const float var  = s2 * inv_d - mean * mean;
    const float rstd = rsqrtf(var + EPS);
    const float nm   = -mean * rstd;

    // ---- pass 2: LDS-read x, 5 row-sums, overwrite LDS with sv=copysign(L2,xs) ----
    float s1 = 0.f, sxd = 0.f, sd = 0.f, sd2 = 0.f, sxd2 = 0.f;
#pragma unroll
    for (int c = 0; c < 16; ++c) {
        float4 f = s4[c * 64 + lane];
        float e0[4] = {f.x, f.y, f.z, f.w};
        float sv[4];
#pragma unroll
        for (int j = 0; j < 4; ++j) {
            float xs   = fmaf(e0[j], rstd, nm);
            float ab   = fabsf(xs);
            float onea = 1.f + ab;
            float L2   = __builtin_amdgcn_logf(onea);   // v_log_f32: log2(1+|xs|)
            float svj  = copysignf(L2, xs);
            sv[j] = svj;
            s1 += svj;                                   // sum sign*L2 (xLN2 later)
            float l  = L2 * LN2;                         // natural log1p
            float dd = fmaf(onea, l, -ab);               // d = (1+|xs|)l1p - |xs|
            sxd = fmaf(xs, dd, sxd);
            sd += dd;
            sd2 = fmaf(dd, dd, sd2);
            float p1 = fmaf(onea, l * l, -(dd + dd));    // (1+|xs|)l1p^2 - 2d
            sxd2 = fmaf(ab, p1, sxd2);                   // xs*d2 = |xs|*p1
        }
        float4 o = {sv[0], sv[1], sv[2], sv[3]};
        s4[c * 64 + lane] = o;                           // same lane, same slot: safe
    }
#pragma unroll
    for (int m = 32; m > 0; m >>= 1) {
        s1   += __shfl_xor(s1,   m, 64);
        sxd  += __shfl_xor(sxd,  m, 64);
        sd   += __shfl_xor(sd,   m, 64);
        sd2  += __shfl_xor(sd2,  m, 64);
        sxd2 += __shfl_xor(sxd2, m, 64);
    }

    // ---- row scalars (every lane, redundant, cheap) ----
    const float s1m   = s1 * (inv_d * LN2);
    const float dvar  = 2.f * sxd * inv_d;
    const float g1    = 0.5f * dvar - s1m;
    const float dmean = sd * inv_d;
    const float vard  = sd2 * inv_d - dmean * dmean;
    const float d2var = 2.f * (sxd2 * inv_d + vard);
    const float g2    = -0.5f * dvar * dvar + 0.5f * d2var;
    const float lm    = 1.f - g1 * __builtin_amdgcn_rcpf(g2 + EPS_SQRT);

    const float eta_p = lm;
    const float eta_n = 2.f - lm;
    const float ep = eta_p + ((eta_p >= 0.f) ? EPS_SQRT : -EPS_SQRT);
    const float en = eta_n + ((eta_n >= 0.f) ? EPS_SQRT : -EPS_SQRT);
    const bool  mp = fabsf(eta_p) <= EPS_SQRT;
    const bool  mn = fabsf(eta_n) <= EPS_SQRT;
    const float rp =  __builtin_amdgcn_rcpf(ep);
    const float rn = -__builtin_amdgcn_rcpf(en);

    float* orow = out + (size_t)row * D;
    const float4* w4 = (const float4*)w;
    const float4* b4 = (const float4*)b;

    // ---- pass 3: LDS-read sv, transform + affine, store ----
    if (!(mp || mn)) {
        // fast path (overwhelmingly common): no tr2/mask selects
#pragma unroll
        for (int c = 0; c < 16; ++c) {
            float4 f  = s4[c * 64 + lane];
            float4 wf = w4[c * 64 + lane];
            float4 bf = b4[c * 64 + lane];
            float sv[4] = {f.x, f.y, f.z, f.w};
            float wa[4] = {wf.x, wf.y, wf.z, wf.w};
            float ba[4] = {bf.x, bf.y, bf.z, bf.w};
            float oa[4];
#pragma unroll
            for (int j = 0; j < 4; ++j) {
                bool pos = (sv[j] >= 0.f);
                float L2 = fabsf(sv[j]);
                float e  = pos ? ep : en;
                float re = pos ? rp : rn;
                // tr1 = re*(exp2(e*L2)-1) = fma(re, exp2, -re)
                float tr = fmaf(re, __builtin_amdgcn_exp2f(e * L2), -re);
                oa[j] = fmaf(tr, wa[j], ba[j]);
            }
            float4 o = {oa[0], oa[1], oa[2], oa[3]};
            ((float4*)orow)[c * 64 + lane] = o;
        }
    } else {
        // general path with small-|eta| fallback
#pragma unroll
        for (int c = 0; c < 16; ++c) {
            float4 f  = s4[c * 64 + lane];
            float4 wf = w4[c * 64 + lane];
            float4 bf = b4[c * 64 + lane];
            float sv[4] = {f.x, f.y, f.z, f.w};
            float wa[4] = {wf.x, wf.y, wf.z, wf.w};
            float ba[4] = {bf.x, bf.y, bf.z, bf.w};
            float oa[4];
#pragma unroll
            for (int j = 0; j < 4; ++j) {
                bool pos = (sv[j] >= 0.f);
                float L2 = fabsf(sv[j]);
                float e  = pos ? ep : en;
                float re = pos ? rp : rn;
                bool  m  = pos ? mp : mn;
                float tr1 = fmaf(re, __builtin_amdgcn_exp2f(e * L2), -re);
                float tr2 = sv[j] * LN2;             // sign * l1p
                float tr  = m ? tr2 : tr1;
                oa[j] = fmaf(tr, wa[j], ba[j]);
            }
            float4 o = {oa[0], oa[1], oa[2], oa[3]};
            ((float4*)orow)[c * 64 + lane] = o;
        }
    }
}

extern "C" void kernel_launch(void* const* d_in, const int* in_sizes, int n_in,
                              void* d_out, int out_size, void* d_ws, size_t ws_size,
                              hipStream_t stream) {
    const float* x = (const float*)d_in[0];
    const float* w = (const float*)d_in[1];
    const float* b = (const float*)d_in[2];
    float* out = (float*)d_out;
    const int rows = in_sizes[0] / D;   // 8192
    lnn_kernel<<<dim3(rows), dim3(NT), 0, stream>>>(x, w, b, out, rows);
}